// Round 10
// baseline (490.415 us; speedup 1.0000x reference)
//
#include <hip/hip_runtime.h>
#include <math.h>

#define B_   128
#define S_   512
#define H_   1024
#define F_   512
#define V_   50000
#define OOV_ 50
#define EV_  (V_ + OOV_)   // 50050

#define BM 128
#define BN 128
#define BK 64

typedef __attribute__((ext_vector_type(8))) __bf16 bf16x8;
typedef __attribute__((ext_vector_type(4))) __bf16 bf16x4;
typedef __attribute__((ext_vector_type(4))) float  f32x4;

__device__ __forceinline__ void gload_lds16(const void* g, void* lds) {
  __builtin_amdgcn_global_load_lds(
      (const __attribute__((address_space(1))) unsigned int*)g,
      (__attribute__((address_space(3))) unsigned int*)lds, 16, 0, 0);
}

__device__ __forceinline__ float fast_tanh(float x) {
  float v = fminf(fmaxf(x, -15.f), 15.f);
  float t = __expf(2.f * v);
  return 1.f - 2.f / (t + 1.f);
}

// ---------------- front kernel: cast (blocks 0..4095) + sWs GEMM (4096..4127) + gi GEMM (4128..4223) ----------------
// cast saturates HBM; the latency-bound GEMM blocks hide in its bandwidth shadow.
// All code inline (no shared-pointer device function — R9's clang segfault candidate).
__global__ __launch_bounds__(256)
void front_kernel(const float* __restrict__ enc, __bf16* __restrict__ enc_h,
                  const float* __restrict__ wh, __bf16* __restrict__ wh_h,
                  const float* __restrict__ hidden, const float* __restrict__ att_Ws,
                  float* __restrict__ sws, const int* __restrict__ input,
                  const float* __restrict__ emb, const float* __restrict__ W_ih,
                  float* __restrict__ gi)
{
  __shared__ float As[128 * 68];
  __shared__ float Ws[32 * 68];
  const int bid = blockIdx.x;
  const int tid = threadIdx.x;
  if (bid < 4096) {
    const size_t n_enc = (size_t)B_ * S_ * H_;
    const size_t n_tot = n_enc + (size_t)H_ * H_;
    for (size_t i = ((size_t)bid * 256 + tid) * 8; i < n_tot;
         i += (size_t)4096 * 256 * 8) {
      const float* in; __bf16* out; size_t j;
      if (i < n_enc) { in = enc; out = enc_h; j = i; }
      else           { in = wh;  out = wh_h;  j = i - n_enc; }
      float4 a = *(const float4*)(in + j);
      float4 b = *(const float4*)(in + j + 4);
      bf16x8 o;
      o[0] = (__bf16)a.x; o[1] = (__bf16)a.y; o[2] = (__bf16)a.z; o[3] = (__bf16)a.w;
      o[4] = (__bf16)b.x; o[5] = (__bf16)b.y; o[6] = (__bf16)b.z; o[7] = (__bf16)b.w;
      *(bf16x8*)(out + j) = o;
    }
    return;
  }
  // GEMM path: block-uniform selection, A-row pointers resolved once (no in-loop ternary)
  const int sel = (bid >= 4128) ? 1 : 0;          // 0: sWs, 1: gi
  const int n0  = sel ? (bid - 4128) * 32 : (bid - 4096) * 32;
  const int N   = sel ? 3 * H_ : H_;
  const int K   = sel ? F_ : H_;
  const float* Wm = sel ? W_ih : att_Ws;
  float* outp = sel ? gi : sws;
  const int tx = tid & 7, ty = tid >> 3;
  const int lr = tid >> 4, lc4 = (tid & 15) * 4;
  const float* arow[8];
#pragma unroll
  for (int pp = 0; pp < 8; ++pp) {
    int m = pp * 16 + lr;
    if (sel) arow[pp] = emb + (size_t)input[m] * F_;
    else     arow[pp] = hidden + (size_t)m * H_;
  }
  float acc[4][4] = {};
  for (int k0 = 0; k0 < K; k0 += 64) {
#pragma unroll
    for (int pp = 0; pp < 8; ++pp)
      *(float4*)(As + (pp * 16 + lr) * 68 + lc4) = *(const float4*)(arow[pp] + k0 + lc4);
#pragma unroll
    for (int pp = 0; pp < 2; ++pp)
      *(float4*)(Ws + (pp * 16 + lr) * 68 + lc4) =
          *(const float4*)(Wm + (size_t)(n0 + pp * 16 + lr) * K + k0 + lc4);
    __syncthreads();
#pragma unroll
    for (int kk = 0; kk < 16; ++kk) {
      float4 av[4], wv[4];
#pragma unroll
      for (int i = 0; i < 4; i++) av[i] = *(const float4*)(As + (ty * 4 + i) * 68 + kk * 4);
#pragma unroll
      for (int j = 0; j < 4; j++) wv[j] = *(const float4*)(Ws + (tx * 4 + j) * 68 + kk * 4);
#pragma unroll
      for (int i = 0; i < 4; i++)
#pragma unroll
        for (int j = 0; j < 4; j++) {
          acc[i][j] = fmaf(av[i].x, wv[j].x, acc[i][j]);
          acc[i][j] = fmaf(av[i].y, wv[j].y, acc[i][j]);
          acc[i][j] = fmaf(av[i].z, wv[j].z, acc[i][j]);
          acc[i][j] = fmaf(av[i].w, wv[j].w, acc[i][j]);
        }
    }
    __syncthreads();
  }
#pragma unroll
  for (int i = 0; i < 4; i++)
#pragma unroll
    for (int j = 0; j < 4; j++)
      outp[(size_t)(ty * 4 + i) * N + n0 + tx * 4 + j] = acc[i][j];
}

// ---------------- split-K fp32 GEMM (used on the dependent chain) ----------------
__global__ __launch_bounds__(256)
void gemm_splitk(const float* __restrict__ A, const float* __restrict__ W,
                 float* __restrict__ partial, int N, int K, int KS)
{
  __shared__ float As[128 * 68];
  __shared__ float Ws[32 * 68];
  const int tid = threadIdx.x;
  const int n0 = blockIdx.x * 32;
  const int p  = blockIdx.y;
  const int tx = tid & 7, ty = tid >> 3;
  const int lr = tid >> 4, lc4 = (tid & 15) * 4;
  float acc[4][4] = {};
  const int kend = p * KS + KS;
  for (int k0 = p * KS; k0 < kend; k0 += 64) {
#pragma unroll
    for (int pp = 0; pp < 8; ++pp)
      *(float4*)(As + (pp * 16 + lr) * 68 + lc4) =
          *(const float4*)(A + (size_t)(pp * 16 + lr) * K + k0 + lc4);
#pragma unroll
    for (int pp = 0; pp < 2; ++pp)
      *(float4*)(Ws + (pp * 16 + lr) * 68 + lc4) =
          *(const float4*)(W + (size_t)(n0 + pp * 16 + lr) * K + k0 + lc4);
    __syncthreads();
#pragma unroll
    for (int kk = 0; kk < 16; ++kk) {
      float4 av[4], wv[4];
#pragma unroll
      for (int i = 0; i < 4; i++) av[i] = *(const float4*)(As + (ty * 4 + i) * 68 + kk * 4);
#pragma unroll
      for (int j = 0; j < 4; j++) wv[j] = *(const float4*)(Ws + (tx * 4 + j) * 68 + kk * 4);
#pragma unroll
      for (int i = 0; i < 4; i++)
#pragma unroll
        for (int j = 0; j < 4; j++) {
          acc[i][j] = fmaf(av[i].x, wv[j].x, acc[i][j]);
          acc[i][j] = fmaf(av[i].y, wv[j].y, acc[i][j]);
          acc[i][j] = fmaf(av[i].z, wv[j].z, acc[i][j]);
          acc[i][j] = fmaf(av[i].w, wv[j].w, acc[i][j]);
        }
    }
    __syncthreads();
  }
#pragma unroll
  for (int i = 0; i < 4; i++)
#pragma unroll
    for (int j = 0; j < 4; j++)
      partial[((size_t)p * 128 + ty * 4 + i) * N + n0 + tx * 4 + j] = acc[i][j];
}

// variant: A = concat(A1[128,1024], A2[128,1024]) along K (KS=128 keeps p in one half)
__global__ __launch_bounds__(256)
void gemm_splitk_cat(const float* __restrict__ A1, const float* __restrict__ A2,
                     const float* __restrict__ W, float* __restrict__ partial,
                     int N, int K, int KS)
{
  __shared__ float As[128 * 68];
  __shared__ float Ws[32 * 68];
  const int tid = threadIdx.x;
  const int n0 = blockIdx.x * 32;
  const int p  = blockIdx.y;
  const int tx = tid & 7, ty = tid >> 3;
  const int lr = tid >> 4, lc4 = (tid & 15) * 4;
  const float* A = (p * KS < 1024) ? A1 : A2;
  const int kbase = (p * KS < 1024) ? 0 : 1024;
  float acc[4][4] = {};
  const int kend = p * KS + KS;
  for (int k0 = p * KS; k0 < kend; k0 += 64) {
#pragma unroll
    for (int pp = 0; pp < 8; ++pp)
      *(float4*)(As + (pp * 16 + lr) * 68 + lc4) =
          *(const float4*)(A + (size_t)(pp * 16 + lr) * 1024 + (k0 - kbase) + lc4);
#pragma unroll
    for (int pp = 0; pp < 2; ++pp)
      *(float4*)(Ws + (pp * 16 + lr) * 68 + lc4) =
          *(const float4*)(W + (size_t)(n0 + pp * 16 + lr) * K + k0 + lc4);
    __syncthreads();
#pragma unroll
    for (int kk = 0; kk < 16; ++kk) {
      float4 av[4], wv[4];
#pragma unroll
      for (int i = 0; i < 4; i++) av[i] = *(const float4*)(As + (ty * 4 + i) * 68 + kk * 4);
#pragma unroll
      for (int j = 0; j < 4; j++) wv[j] = *(const float4*)(Ws + (tx * 4 + j) * 68 + kk * 4);
#pragma unroll
      for (int i = 0; i < 4; i++)
#pragma unroll
        for (int j = 0; j < 4; j++) {
          acc[i][j] = fmaf(av[i].x, wv[j].x, acc[i][j]);
          acc[i][j] = fmaf(av[i].y, wv[j].y, acc[i][j]);
          acc[i][j] = fmaf(av[i].z, wv[j].z, acc[i][j]);
          acc[i][j] = fmaf(av[i].w, wv[j].w, acc[i][j]);
        }
    }
    __syncthreads();
  }
#pragma unroll
  for (int i = 0; i < 4; i++)
#pragma unroll
    for (int j = 0; j < 4; j++)
      partial[((size_t)p * 128 + ty * 4 + i) * N + n0 + tx * 4 + j] = acc[i][j];
}

__global__ __launch_bounds__(256)
void reduce_partial(const float* __restrict__ partial, const float* __restrict__ bias,
                    float* __restrict__ C, int N, int P)
{
  int idx = blockIdx.x * 256 + threadIdx.x;
  int n = idx % N;
  float s = bias ? bias[n] : 0.f;
  for (int p = 0; p < P; ++p) s += partial[(size_t)p * 128 * N + idx];
  C[idx] = s;
}

__global__ __launch_bounds__(256)
void reduce_partial_bf16(const float* __restrict__ partial, const float* __restrict__ bias,
                         __bf16* __restrict__ C, int N, int P)
{
  int idx = blockIdx.x * 256 + threadIdx.x;
  int n = idx % N;
  float s = bias ? bias[n] : 0.f;
  for (int p = 0; p < P; ++p) s += partial[(size_t)p * 128 * N + idx];
  C[idx] = (__bf16)s;
}

// ------------- 256^2 8-phase MFMA attention feature GEMM (T3+T4+T5) — unchanged from R8 -------------
__global__ __launch_bounds__(512, 1)
void feat_mfma256_kernel(const __bf16* __restrict__ enc, const __bf16* __restrict__ Wh,
                         const float* __restrict__ sws, const float* __restrict__ cov,
                         const float* __restrict__ wcv, const float* __restrict__ ab,
                         const float* __restrict__ av_, float* __restrict__ e_part)
{
  __shared__ __attribute__((aligned(16))) __bf16 As[2][2][128 * 64];  // [dbuf][m-half]
  __shared__ __attribute__((aligned(16))) __bf16 Bs[2][2][128 * 64];  // [dbuf][n-half]
  const int tid  = threadIdx.x;
  const int lane = tid & 63, wid = tid >> 6;   // 8 waves
  const int wr = wid >> 2, wc = wid & 3;       // 2 x 4; wave owns 128x64 output
  const int bid = blockIdx.x;
  const int swz = (bid & 7) * 128 + (bid >> 3);  // bijective XCD swizzle (nwg=1024)
  const int mt = swz >> 2, nt = swz & 3;
  const int bs0 = mt * 256;
  const int n0  = nt * 256;
  const int b   = bs0 >> 9;

  const int scb = ((tid & 7) * 16) ^ (((tid >> 3) & 7) << 4);
  const __bf16* aS[2][2];
  const __bf16* bS[2][2];
#pragma unroll
  for (int h = 0; h < 2; ++h)
#pragma unroll
    for (int q = 0; q < 2; ++q) {
      int r = h * 128 + q * 64 + (tid >> 3);
      aS[h][q] = enc + (size_t)(bs0 + r) * H_ + (scb >> 1);
      bS[h][q] = Wh  + (size_t)(n0  + r) * H_ + (scb >> 1);
    }
  const int ldsQ0 = tid * 16, ldsQ1 = 8192 + tid * 16;

  const int lrow = lane & 15, kbase = (lane >> 4) << 4;
  const int bh = wc >> 1;
  int aO[8][2], bO[4][2];
#pragma unroll
  for (int m = 0; m < 8; ++m) {
    int rh = m * 16 + lrow, sw = (rh & 7) << 4;
    aO[m][0] = rh * 128 + (kbase ^ sw);
    aO[m][1] = rh * 128 + ((64 + kbase) ^ sw);
  }
#pragma unroll
  for (int n = 0; n < 4; ++n) {
    int rh = (wc & 1) * 64 + n * 16 + lrow, sw = (rh & 7) << 4;
    bO[n][0] = rh * 128 + (kbase ^ sw);
    bO[n][1] = rh * 128 + ((64 + kbase) ^ sw);
  }

  f32x4 acc[8][4];
#pragma unroll
  for (int i = 0; i < 8; i++)
#pragma unroll
    for (int j = 0; j < 4; j++) acc[i][j] = (f32x4){0.f, 0.f, 0.f, 0.f};
  bf16x8 bfv[4][2];

#define STG_A(d, h, ofs)                                                       \
  { gload_lds16(aS[h][0] + (ofs), (char*)As[d][h] + ldsQ0);                    \
    gload_lds16(aS[h][1] + (ofs), (char*)As[d][h] + ldsQ1); }
#define STG_B(d, h, ofs)                                                       \
  { gload_lds16(bS[h][0] + (ofs), (char*)Bs[d][h] + ldsQ0);                    \
    gload_lds16(bS[h][1] + (ofs), (char*)Bs[d][h] + ldsQ1); }
#define BAR()                                                                  \
  { __builtin_amdgcn_sched_barrier(0); __builtin_amdgcn_s_barrier();           \
    __builtin_amdgcn_sched_barrier(0); }
#define LGKM0()                                                                \
  { asm volatile("s_waitcnt lgkmcnt(0)" ::: "memory");                         \
    __builtin_amdgcn_sched_barrier(0); }
#define VMC(n)                                                                 \
  { asm volatile("s_waitcnt vmcnt(" #n ")" ::: "memory");                      \
    __builtin_amdgcn_sched_barrier(0); }
#define RD_B(d)                                                                \
  { _Pragma("unroll")                                                          \
    for (int n = 0; n < 4; ++n) {                                              \
      bfv[n][0] = *(const bf16x8*)((const char*)Bs[d][bh] + bO[n][0]);         \
      bfv[n][1] = *(const bf16x8*)((const char*)Bs[d][bh] + bO[n][1]);         \
    } }
#define PH(d, q, STGSTMT, TAILWAIT)                                            \
  {                                                                            \
    bf16x8 x00 = *(const bf16x8*)((const char*)As[d][wr] + aO[2*(q)][0]);      \
    bf16x8 x01 = *(const bf16x8*)((const char*)As[d][wr] + aO[2*(q)][1]);      \
    bf16x8 x10 = *(const bf16x8*)((const char*)As[d][wr] + aO[2*(q)+1][0]);    \
    bf16x8 x11 = *(const bf16x8*)((const char*)As[d][wr] + aO[2*(q)+1][1]);    \
    STGSTMT;                                                                   \
    BAR(); LGKM0();                                                            \
    __builtin_amdgcn_s_setprio(1);                                             \
    _Pragma("unroll")                                                          \
    for (int n = 0; n < 4; ++n) {                                              \
      acc[2*(q)][n]   = __builtin_amdgcn_mfma_f32_16x16x32_bf16(x00, bfv[n][0], acc[2*(q)][n], 0, 0, 0);   \
      acc[2*(q)][n]   = __builtin_amdgcn_mfma_f32_16x16x32_bf16(x01, bfv[n][1], acc[2*(q)][n], 0, 0, 0);   \
      acc[2*(q)+1][n] = __builtin_amdgcn_mfma_f32_16x16x32_bf16(x10, bfv[n][0], acc[2*(q)+1][n], 0, 0, 0); \
      acc[2*(q)+1][n] = __builtin_amdgcn_mfma_f32_16x16x32_bf16(x11, bfv[n][1], acc[2*(q)+1][n], 0, 0, 0); \
    }                                                                          \
    __builtin_amdgcn_s_setprio(0);                                             \
    TAILWAIT; BAR();                                                           \
  }

  STG_B(0, 0, 0) STG_B(0, 1, 0) STG_A(0, 0, 0) STG_A(0, 1, 0)
  STG_B(1, 0, 64) STG_B(1, 1, 64)
  VMC(4); BAR();

#pragma unroll 1
  for (int i = 0; i < 7; ++i) {
    RD_B(0);
    PH(0, 0, STG_A(1, 0, 64), )
    PH(0, 1, STG_A(1, 1, 64), )
    PH(0, 2, STG_B(0, 0, 128), )
    PH(0, 3, STG_B(0, 1, 128), VMC(4))
    RD_B(1);
    PH(1, 0, STG_A(0, 0, 128), )
    PH(1, 1, STG_A(0, 1, 128), )
    PH(1, 2, STG_B(1, 0, 192), )
    PH(1, 3, STG_B(1, 1, 192), VMC(4))
#pragma unroll
    for (int h = 0; h < 2; ++h)
#pragma unroll
      for (int q = 0; q < 2; ++q) { aS[h][q] += 128; bS[h][q] += 128; }
  }
  RD_B(0);
  PH(0, 0, STG_A(1, 0, 64), )
  PH(0, 1, STG_A(1, 1, 64), )
  PH(0, 2, , )
  PH(0, 3, , VMC(0))
  RD_B(1);
  PH(1, 0, , )
  PH(1, 1, , )
  PH(1, 2, , )
  PH(1, 3, , )
  __syncthreads();
#undef STG_A
#undef STG_B
#undef BAR
#undef LGKM0
#undef VMC
#undef RD_B
#undef PH

  float rowsum[8][4];
#pragma unroll
  for (int m = 0; m < 8; m++)
#pragma unroll
    for (int j = 0; j < 4; j++) rowsum[m][j] = 0.f;

#pragma unroll
  for (int n = 0; n < 4; ++n) {
    int col_g = n0 + wc * 64 + n * 16 + (lane & 15);
    float sw   = sws[(size_t)b * H_ + col_g];
    float wc_n = wcv[col_g], ab_n = ab[col_g], av_n = av_[col_g];
#pragma unroll
    for (int m = 0; m < 8; ++m) {
#pragma unroll
      for (int j = 0; j < 4; ++j) {
        int row_l = wr * 128 + m * 16 + ((lane >> 4) << 2) + j;
        float val = acc[m][n][j] + sw + cov[bs0 + row_l] * wc_n + ab_n;
        rowsum[m][j] += fast_tanh(val) * av_n;
      }
    }
  }
#pragma unroll
  for (int m = 0; m < 8; ++m)
#pragma unroll
    for (int j = 0; j < 4; ++j) {
      float v = rowsum[m][j];
      v += __shfl_xor(v, 1);
      v += __shfl_xor(v, 2);
      v += __shfl_xor(v, 4);
      v += __shfl_xor(v, 8);
      rowsum[m][j] = v;
    }
  float (*red)[4] = (float(*)[4])As;
  if ((lane & 15) == 0) {
#pragma unroll
    for (int m = 0; m < 8; ++m)
#pragma unroll
      for (int j = 0; j < 4; ++j)
        red[wr * 128 + m * 16 + ((lane >> 4) << 2) + j][wc] = rowsum[m][j];
  }
  __syncthreads();
  if (tid < 256)
    e_part[(size_t)nt * (B_ * S_) + bs0 + tid] =
        red[tid][0] + red[tid][1] + red[tid][2] + red[tid][3];
}

// ------------- MFMA logits GEMM with reg-prefetch of next W k-slice -------------
__global__ __launch_bounds__(256)
void logits_mfma_kernel(const __bf16* __restrict__ A, const float* __restrict__ W,
                        const float* __restrict__ bias, float* __restrict__ out0)
{
  __shared__ __attribute__((aligned(16))) __bf16 As[BM * BK];
  __shared__ __attribute__((aligned(16))) __bf16 Bs[BN * BK];
  const int tid  = threadIdx.x;
  const int lane = tid & 63, wid = tid >> 6;
  const int wr = wid >> 1, wcc = wid & 1;
  const int n0 = blockIdx.x * BN;

  f32x4 acc[4][4];
#pragma unroll
  for (int i = 0; i < 4; i++)
#pragma unroll
    for (int j = 0; j < 4; j++) acc[i][j] = (f32x4){0.f, 0.f, 0.f, 0.f};

  const float* wsrc[8];
  int wdst[8];
#pragma unroll
  for (int p = 0; p < 8; ++p) {
    int idx = p * 1024 + tid * 4;
    int r = idx >> 6, c = idx & 63;
    int row_g = n0 + r; if (row_g >= V_) row_g = V_ - 1;
    wsrc[p] = W + (size_t)row_g * F_ + c;
    wdst[p] = r * 128 + ((c * 2) ^ ((r & 7) << 4));
  }
  float4 wreg[8];
#pragma unroll
  for (int p = 0; p < 8; ++p) wreg[p] = *(const float4*)(wsrc[p]);

  for (int k0 = 0; k0 < F_; k0 += BK) {
#pragma unroll
    for (int p = 0; p < 4; ++p) {
      int off = p * 4096 + tid * 16;
      int r = off >> 7, cb = off & 127;
      int scb = cb ^ ((r & 7) << 4);
      gload_lds16(A + (size_t)r * F_ + k0 + (scb >> 1), (char*)As + off);
    }
#pragma unroll
    for (int p = 0; p < 8; ++p) {
      union { __bf16 h[4]; uint2 u; } t;
      t.h[0] = (__bf16)wreg[p].x; t.h[1] = (__bf16)wreg[p].y;
      t.h[2] = (__bf16)wreg[p].z; t.h[3] = (__bf16)wreg[p].w;
      *(uint2*)((char*)Bs + wdst[p]) = t.u;
    }
    __syncthreads();
    if (k0 + BK < F_) {
#pragma unroll
      for (int p = 0; p < 8; ++p) wreg[p] = *(const float4*)(wsrc[p] + k0 + BK);
    }

    bf16x8 af[4][2], bfv[4][2];
#pragma unroll
    for (int m = 0; m < 4; ++m) {
      int row = wr * 64 + m * 16 + (lane & 15);
      int swz = (row & 7) << 4;
#pragma unroll
      for (int kk = 0; kk < 2; ++kk) {
        int kb = kk * 64 + ((lane >> 4) << 4);
        af[m][kk] = *(const bf16x8*)((const char*)As + row * 128 + (kb ^ swz));
      }
    }
#pragma unroll
    for (int n = 0; n < 4; ++n) {
      int row = wcc * 64 + n * 16 + (lane & 15);
      int swz = (row & 7) << 4;
#pragma unroll
      for (int kk = 0; kk < 2; ++kk) {
        int kb = kk * 64 + ((lane >> 4) << 4);
        bfv[n][kk] = *(const bf16x8*)((const char*)Bs + row * 128 + (kb ^ swz));
      }
    }
#pragma unroll
    for (int m = 0; m < 4; ++m)
#pragma unroll
      for (int n = 0; n < 4; ++n)
#pragma unroll
        for (int kk = 0; kk < 2; ++kk)
          acc[m][n] = __builtin_amdgcn_mfma_f32_16x16x32_bf16(af[m][kk], bfv[n][kk], acc[m][n], 0, 0, 0);
    __syncthreads();
  }

#pragma unroll
  for (int m = 0; m < 4; ++m) {
#pragma unroll
    for (int n = 0; n < 4; ++n) {
      int col_g = n0 + wcc * 64 + n * 16 + (lane & 15);
      if (col_g >= V_) continue;
      float bv = bias[col_g];
#pragma unroll
      for (int j = 0; j < 4; ++j) {
        int row = wr * 64 + m * 16 + ((lane >> 4) << 2) + j;
        out0[(size_t)row * EV_ + col_g] = acc[m][n][j] + bv;
      }
    }
  }
}

// ---------------- softmax over S + renorm + coverage ----------------
__global__ __launch_bounds__(512)
void softmax_a_kernel(const float* __restrict__ e_part, const float* __restrict__ mask,
                      const float* __restrict__ cov, float* __restrict__ a_ws,
                      float* __restrict__ out_a, float* __restrict__ out_cov)
{
  const int b = blockIdx.x;
  const int s = threadIdx.x;
  __shared__ float red[512];
  float e = 0.f;
  for (int kt = 0; kt < 4; ++kt) e += e_part[(size_t)kt * (B_ * S_) + b * S_ + s];
  red[s] = e;
  __syncthreads();
  for (int st = 256; st > 0; st >>= 1) {
    if (s < st) red[s] = fmaxf(red[s], red[s + st]);
    __syncthreads();
  }
  float mx = red[0];
  __syncthreads();
  float ex = expf(e - mx) * mask[b * S_ + s];
  red[s] = ex;
  __syncthreads();
  for (int st = 256; st > 0; st >>= 1) {
    if (s < st) red[s] += red[s + st];
    __syncthreads();
  }
  float a = ex / red[0];
  a_ws[b * S_ + s] = a;
  out_a[b * S_ + s] = a;
  out_cov[b * S_ + s] = cov[b * S_ + s] + a;
}

// ---------------- context[b,h] = sum_s a[b,s] * enc_h[b,s,h]  (bf16 enc) ----------------
__global__ __launch_bounds__(256)
void context_kernel(const float* __restrict__ a_ws, const __bf16* __restrict__ enc,
                    float* __restrict__ ctx)
{
  const int b = blockIdx.y, q = blockIdx.x;
  const int lane = threadIdx.x & 63, w = threadIdx.x >> 6;
  const int h0 = q * 256 + lane * 4;
  __shared__ float al[S_];
  __shared__ float part[4][256];
  for (int i = threadIdx.x; i < S_; i += 256) al[i] = a_ws[b * S_ + i];
  __syncthreads();
  float acc0 = 0.f, acc1 = 0.f, acc2 = 0.f, acc3 = 0.f;
  const __bf16* ep = enc + (size_t)b * S_ * H_ + h0;
#pragma unroll 4
  for (int s = w * 128; s < w * 128 + 128; ++s) {
    bf16x4 v = *(const bf16x4*)(ep + (size_t)s * H_);
    float a = al[s];
    acc0 = fmaf(a, (float)v[0], acc0);
    acc1 = fmaf(a, (float)v[1], acc1);
    acc2 = fmaf(a, (float)v[2], acc2);
    acc3 = fmaf(a, (float)v[3], acc3);
  }
  part[w][lane * 4 + 0] = acc0;
  part[w][lane * 4 + 1] = acc1;
  part[w][lane * 4 + 2] = acc2;
  part[w][lane * 4 + 3] = acc3;
  __syncthreads();
  if (threadIdx.x < 256) {
    int o = threadIdx.x;
    ctx[b * H_ + q * 256 + o] = part[0][o] + part[1][o] + part[2][o] + part[3][o];
  }
}

// ---------------- GRU: gi direct + gh split-K partials folded ----------------
__global__ __launch_bounds__(256)
void gru_kernel(const float* __restrict__ gi, const float* __restrict__ pgh,
                const float* __restrict__ b_ih, const float* __restrict__ b_hh,
                const float* __restrict__ h_att, float* __restrict__ h_new_ws,
                float* __restrict__ out_h)
{
  int idx = blockIdx.x * 256 + threadIdx.x;
  int b = idx >> 10, h = idx & 1023;
  const float* gp = gi + (size_t)b * 3072;
  float ir = b_ih[h] + gp[h];
  float iz = b_ih[H_ + h] + gp[H_ + h];
  float in_ = b_ih[2 * H_ + h] + gp[2 * H_ + h];
  float hr = b_hh[h], hz = b_hh[H_ + h], hn = b_hh[2 * H_ + h];
#pragma unroll
  for (int p = 0; p < 8; ++p) {
    const float* hp = pgh + (size_t)p * 128 * 3072 + (size_t)b * 3072;
    hr += hp[h]; hz += hp[H_ + h]; hn += hp[2 * H_ + h];
  }
  float r = 1.f / (1.f + expf(-(ir + hr)));
  float z = 1.f / (1.f + expf(-(iz + hz)));
  float n = tanhf(in_ + r * hn);
  float ha = h_att[(size_t)b * H_ + h];
  float hv = (1.f - z) * n + z * ha;
  h_new_ws[idx] = hv;
  out_h[idx] = hv;
}

// ---------------- merged vocab-stats (blocks 0..B-1, float2) + pgen (blocks B..2B-1) ----------------
__global__ __launch_bounds__(512)
void stats_pgen_kernel(const float* __restrict__ logits, float* __restrict__ vmax,
                       float* __restrict__ vsum, const float* __restrict__ context,
                       const float* __restrict__ h_new, const int* __restrict__ input,
                       const float* __restrict__ emb, const float* __restrict__ wgen_w,
                       const float* __restrict__ wgen_b, float* __restrict__ pgen)
{
  __shared__ float red[512];
  if (blockIdx.x < B_) {
    int b = blockIdx.x;
    const float* row = logits + (size_t)b * EV_;
    float m = -1e30f;
    for (int v = threadIdx.x * 2; v < V_; v += 1024) {
      float2 x = *(const float2*)(row + v);
      m = fmaxf(m, fmaxf(x.x, x.y));
    }
    red[threadIdx.x] = m;
    __syncthreads();
    for (int st = 256; st > 0; st >>= 1) {
      if (threadIdx.x < st) red[threadIdx.x] = fmaxf(red[threadIdx.x], red[threadIdx.x + st]);
      __syncthreads();
    }
    m = red[0];
    __syncthreads();
    float ssum = 0.f;
    for (int v = threadIdx.x * 2; v < V_; v += 1024) {
      float2 x = *(const float2*)(row + v);
      ssum += expf(x.x - m) + expf(x.y - m);
    }
    red[threadIdx.x] = ssum;
    __syncthreads();
    for (int st = 256; st > 0; st >>= 1) {
      if (threadIdx.x < st) red[threadIdx.x] += red[threadIdx.x + st];
      __syncthreads();
    }
    if (threadIdx.x == 0) { vmax[b] = m; vsum[b] = red[0]; }
  } else {
    int b = blockIdx.x - B_;
    const float* erow = emb + (size_t)input[b] * F_;
    float acc = 0.f;
    for (int j = threadIdx.x; j < H_; j += 512) acc = fmaf(context[b * H_ + j], wgen_w[j], acc);
    for (int j = threadIdx.x; j < H_; j += 512) acc = fmaf(h_new[b * H_ + j], wgen_w[H_ + j], acc);
    for (int j = threadIdx.x; j < F_; j += 512) acc = fmaf(erow[j], wgen_w[2 * H_ + j], acc);
    red[threadIdx.x] = acc;
    __syncthreads();
    for (int st = 256; st > 0; st >>= 1) {
      if (threadIdx.x < st) red[threadIdx.x] += red[threadIdx.x + st];
      __syncthreads();
    }
    if (threadIdx.x == 0) {
      float p = 1.f / (1.f + expf(-(red[0] + wgen_b[0])));
      p = fminf(fmaxf(p, 0.001f), 0.999f);
      pgen[b] = p;
    }
  }
}

__global__ void final_kernel(float* __restrict__ out0, const float* __restrict__ vmax,
                             const float* __restrict__ vsum, const float* __restrict__ pgen)
{
  int b = blockIdx.y;
  int v = blockIdx.x * 256 + threadIdx.x;
  if (v >= EV_) return;
  float* row = out0 + (size_t)b * EV_;
  if (v < V_) row[v] = pgen[b] * expf(row[v] - vmax[b]) / vsum[b];
  else row[v] = 0.f;
}

__global__ void scatter_kernel(const int* __restrict__ ref2tgt, const float* __restrict__ a_ws,
                               const float* __restrict__ pgen, float* __restrict__ out0)
{
  int b = blockIdx.x;
  int s = threadIdx.x;
  float w = (1.f - pgen[b]) * a_ws[b * S_ + s];
  int t = ref2tgt[b * S_ + s];
  atomicAdd(&out0[(size_t)b * EV_ + t], w);
}

extern "C" void kernel_launch(void* const* d_in, const int* in_sizes, int n_in,
                              void* d_out, int out_size, void* d_ws, size_t ws_size,
                              hipStream_t stream)
{
  const int*   input   = (const int*)d_in[0];
  const float* hidden  = (const float*)d_in[1];
  const float* enc     = (const float*)d_in[2];
  const float* mask    = (const float*)d_in[3];
  const float* cov     = (const float*)d_in[5];
  const int*   ref2tgt = (const int*)d_in[6];
  const float* emb     = (const float*)d_in[7];
  const float* W_ih    = (const float*)d_in[8];
  const float* W_hh    = (const float*)d_in[9];
  const float* b_ih    = (const float*)d_in[10];
  const float* b_hh    = (const float*)d_in[11];
  const float* e2v1_w  = (const float*)d_in[12];
  const float* e2v1_b  = (const float*)d_in[13];
  const float* e2v2_w  = (const float*)d_in[14];
  const float* e2v2_b  = (const float*)d_in[15];
  const float* fc_w    = (const float*)d_in[16];
  const float* fc_b    = (const float*)d_in[17];
  const float* wgen_w  = (const float*)d_in[18];
  const float* wgen_b  = (const float*)d_in[19];
  const float* att_Wh  = (const float*)d_in[20];
  const float* att_Ws  = (const float*)d_in[21];
  const float* att_wc  = (const float*)d_in[22];
  const float* att_b   = (const float*)d_in[23];
  const float* att_v   = (const float*)d_in[24];

  char* w = (char*)d_ws;
  __bf16* enc_h  = (__bf16*)w;  w += (size_t)B_ * S_ * H_ * 2;   // 134.2 MB
  __bf16* Wh_h   = (__bf16*)w;  w += (size_t)H_ * H_ * 2;        // 2 MB
  __bf16* out1_h = (__bf16*)w;  w += (size_t)B_ * F_ * 2;
  float* sws     = (float*)w;   w += (size_t)B_ * H_ * 4;
  float* gi      = (float*)w;   w += (size_t)B_ * 3 * H_ * 4;    // 1.5 MB direct
  float* e_part  = (float*)w;   w += (size_t)4 * B_ * S_ * 4;
  float* a_ws    = (float*)w;   w += (size_t)B_ * S_ * 4;
  float* context = (float*)w;   w += (size_t)B_ * H_ * 4;
  float* h_att   = (float*)w;   w += (size_t)B_ * H_ * 4;
  float* h_new   = (float*)w;   w += (size_t)B_ * H_ * 4;
  float* pgen    = (float*)w;   w += 128 * 4;
  float* vmax    = (float*)w;   w += 128 * 4;
  float* vsum    = (float*)w;   w += 128 * 4;
  float* pA      = (float*)w;   w += (size_t)16 * 128 * 1024 * 4;  // 8 MB (fc / out1 partials)
  float* pC      = (float*)w;   w += (size_t)8 * 128 * 3072 * 4;   // 12.6 MB (gh partials)

  float* out0    = (float*)d_out;
  float* out_h   = out0 + (size_t)B_ * EV_;
  float* out_cov = out_h + (size_t)B_ * H_;
  float* out_a   = out_cov + (size_t)B_ * S_;

  // 1. front: bf16 casts (HBM-bound) + sWs GEMM + gi GEMM co-scheduled
  front_kernel<<<4224, 256, 0, stream>>>(enc, enc_h, att_Wh, Wh_h,
                                         hidden, att_Ws, sws, input, emb, W_ih, gi);
  // 2. fused attention feature GEMM (256^2, 8-phase)
  feat_mfma256_kernel<<<dim3(1024), 512, 0, stream>>>(enc_h, Wh_h, sws, cov, att_wc, att_b, att_v, e_part);
  // 3. softmax + coverage
  softmax_a_kernel<<<B_, 512, 0, stream>>>(e_part, mask, cov, a_ws, out_a, out_cov);
  // 4. context from bf16 enc
  context_kernel<<<dim3(4, B_), 256, 0, stream>>>(a_ws, enc_h, context);
  // 5. h_att = [hidden, context] @ fc_w^T + fc_b
  gemm_splitk_cat<<<dim3(32, 16), 256, 0, stream>>>(hidden, context, fc_w, pA, H_, 2 * H_, 128);
  reduce_partial<<<512, 256, 0, stream>>>(pA, fc_b, h_att, H_, 16);
  // 6. gh partials + GRU (gi direct, gh reduction folded)
  gemm_splitk<<<dim3(96, 8), 256, 0, stream>>>(h_att, W_hh, pC, 3 * H_, H_, 128);
  gru_kernel<<<(B_ * H_) / 256, 256, 0, stream>>>(gi, pC, b_ih, b_hh, h_att, h_new, out_h);
  // 7. out1 = h_new @ e2v1^T + b  (reduce straight to bf16)
  gemm_splitk<<<dim3(16, 16), 256, 0, stream>>>(h_new, e2v1_w, pA, F_, H_, 64);
  reduce_partial_bf16<<<256, 256, 0, stream>>>(pA, e2v1_b, out1_h, F_, 16);
  // 8. vocab logits + merged stats/pgen + pointer mix
  logits_mfma_kernel<<<dim3((V_ + BN - 1) / BN), 256, 0, stream>>>(out1_h, e2v2_w, e2v2_b, out0);
  stats_pgen_kernel<<<2 * B_, 512, 0, stream>>>(out0, vmax, vsum, context, h_new, input, emb,
                                                wgen_w, wgen_b, pgen);
  final_kernel<<<dim3((EV_ + 255) / 256, B_), 256, 0, stream>>>(out0, vmax, vsum, pgen);
  scatter_kernel<<<B_, 512, 0, stream>>>(ref2tgt, a_ws, pgen, out0);
}

// Round 11
// 445.109 us; speedup vs baseline: 1.1018x; 1.1018x over previous
//
#include <hip/hip_runtime.h>
#include <math.h>

#define B_   128
#define S_   512
#define H_   1024
#define F_   512
#define V_   50000
#define OOV_ 50
#define EV_  (V_ + OOV_)   // 50050

#define BM 128
#define BN 128
#define BK 64

typedef __attribute__((ext_vector_type(8))) __bf16 bf16x8;
typedef __attribute__((ext_vector_type(4))) __bf16 bf16x4;
typedef __attribute__((ext_vector_type(4))) float  f32x4;

__device__ __forceinline__ void gload_lds16(const void* g, void* lds) {
  __builtin_amdgcn_global_load_lds(
      (const __attribute__((address_space(1))) unsigned int*)g,
      (__attribute__((address_space(3))) unsigned int*)lds, 16, 0, 0);
}

__device__ __forceinline__ float fast_tanh(float x) {
  float v = fminf(fmaxf(x, -15.f), 15.f);
  float t = __expf(2.f * v);
  return 1.f - 2.f / (t + 1.f);
}

// ---------------- combined fp32 -> bf16 cast: enc then Wh (no LDS -> full occupancy) ----------------
__global__ __launch_bounds__(256)
void cast_both_kernel(const float* __restrict__ enc, __bf16* __restrict__ enc_h,
                      const float* __restrict__ wh, __bf16* __restrict__ wh_h)
{
  const size_t n_enc = (size_t)B_ * S_ * H_;
  const size_t n_tot = n_enc + (size_t)H_ * H_;
  for (size_t i = ((size_t)blockIdx.x * 256 + threadIdx.x) * 8; i < n_tot;
       i += (size_t)gridDim.x * 256 * 8) {
    const float* in; __bf16* out; size_t j;
    if (i < n_enc) { in = enc; out = enc_h; j = i; }
    else           { in = wh;  out = wh_h;  j = i - n_enc; }
    float4 a = *(const float4*)(in + j);
    float4 b = *(const float4*)(in + j + 4);
    bf16x8 o;
    o[0] = (__bf16)a.x; o[1] = (__bf16)a.y; o[2] = (__bf16)a.z; o[3] = (__bf16)a.w;
    o[4] = (__bf16)b.x; o[5] = (__bf16)b.y; o[6] = (__bf16)b.z; o[7] = (__bf16)b.w;
    *(bf16x8*)(out + j) = o;
  }
}

// ---------------- split-K fp32 GEMM core ----------------
__global__ __launch_bounds__(256)
void gemm_splitk(const float* __restrict__ A, const float* __restrict__ W,
                 float* __restrict__ partial, int N, int K, int KS)
{
  __shared__ float As[128 * 68];
  __shared__ float Ws[32 * 68];
  const int tid = threadIdx.x;
  const int n0 = blockIdx.x * 32;
  const int p  = blockIdx.y;
  const int tx = tid & 7, ty = tid >> 3;
  const int lr = tid >> 4, lc4 = (tid & 15) * 4;
  float acc[4][4] = {};
  const int kend = p * KS + KS;
  for (int k0 = p * KS; k0 < kend; k0 += 64) {
#pragma unroll
    for (int pp = 0; pp < 8; ++pp)
      *(float4*)(As + (pp * 16 + lr) * 68 + lc4) =
          *(const float4*)(A + (size_t)(pp * 16 + lr) * K + k0 + lc4);
#pragma unroll
    for (int pp = 0; pp < 2; ++pp)
      *(float4*)(Ws + (pp * 16 + lr) * 68 + lc4) =
          *(const float4*)(W + (size_t)(n0 + pp * 16 + lr) * K + k0 + lc4);
    __syncthreads();
#pragma unroll
    for (int kk = 0; kk < 16; ++kk) {
      float4 av[4], wv[4];
#pragma unroll
      for (int i = 0; i < 4; i++) av[i] = *(const float4*)(As + (ty * 4 + i) * 68 + kk * 4);
#pragma unroll
      for (int j = 0; j < 4; j++) wv[j] = *(const float4*)(Ws + (tx * 4 + j) * 68 + kk * 4);
#pragma unroll
      for (int i = 0; i < 4; i++)
#pragma unroll
        for (int j = 0; j < 4; j++) {
          acc[i][j] = fmaf(av[i].x, wv[j].x, acc[i][j]);
          acc[i][j] = fmaf(av[i].y, wv[j].y, acc[i][j]);
          acc[i][j] = fmaf(av[i].z, wv[j].z, acc[i][j]);
          acc[i][j] = fmaf(av[i].w, wv[j].w, acc[i][j]);
        }
    }
    __syncthreads();
  }
#pragma unroll
  for (int i = 0; i < 4; i++)
#pragma unroll
    for (int j = 0; j < 4; j++)
      partial[((size_t)p * 128 + ty * 4 + i) * N + n0 + tx * 4 + j] = acc[i][j];
}

// variant: A = concat(A1[128,1024], A2[128,1024]) along K (KS=128 keeps p in one half)
__global__ __launch_bounds__(256)
void gemm_splitk_cat(const float* __restrict__ A1, const float* __restrict__ A2,
                     const float* __restrict__ W, float* __restrict__ partial,
                     int N, int K, int KS)
{
  __shared__ float As[128 * 68];
  __shared__ float Ws[32 * 68];
  const int tid = threadIdx.x;
  const int n0 = blockIdx.x * 32;
  const int p  = blockIdx.y;
  const int tx = tid & 7, ty = tid >> 3;
  const int lr = tid >> 4, lc4 = (tid & 15) * 4;
  const float* A = (p * KS < 1024) ? A1 : A2;
  const int kbase = (p * KS < 1024) ? 0 : 1024;
  float acc[4][4] = {};
  const int kend = p * KS + KS;
  for (int k0 = p * KS; k0 < kend; k0 += 64) {
#pragma unroll
    for (int pp = 0; pp < 8; ++pp)
      *(float4*)(As + (pp * 16 + lr) * 68 + lc4) =
          *(const float4*)(A + (size_t)(pp * 16 + lr) * 1024 + (k0 - kbase) + lc4);
#pragma unroll
    for (int pp = 0; pp < 2; ++pp)
      *(float4*)(Ws + (pp * 16 + lr) * 68 + lc4) =
          *(const float4*)(W + (size_t)(n0 + pp * 16 + lr) * K + k0 + lc4);
    __syncthreads();
#pragma unroll
    for (int kk = 0; kk < 16; ++kk) {
      float4 av[4], wv[4];
#pragma unroll
      for (int i = 0; i < 4; i++) av[i] = *(const float4*)(As + (ty * 4 + i) * 68 + kk * 4);
#pragma unroll
      for (int j = 0; j < 4; j++) wv[j] = *(const float4*)(Ws + (tx * 4 + j) * 68 + kk * 4);
#pragma unroll
      for (int i = 0; i < 4; i++)
#pragma unroll
        for (int j = 0; j < 4; j++) {
          acc[i][j] = fmaf(av[i].x, wv[j].x, acc[i][j]);
          acc[i][j] = fmaf(av[i].y, wv[j].y, acc[i][j]);
          acc[i][j] = fmaf(av[i].z, wv[j].z, acc[i][j]);
          acc[i][j] = fmaf(av[i].w, wv[j].w, acc[i][j]);
        }
    }
    __syncthreads();
  }
#pragma unroll
  for (int i = 0; i < 4; i++)
#pragma unroll
    for (int j = 0; j < 4; j++)
      partial[((size_t)p * 128 + ty * 4 + i) * N + n0 + tx * 4 + j] = acc[i][j];
}

// variant: A rows gathered from emb via input[]
__global__ __launch_bounds__(256)
void gemm_splitk_gather(const int* __restrict__ input, const float* __restrict__ emb,
                        const float* __restrict__ W, float* __restrict__ partial,
                        int N, int K, int KS)
{
  __shared__ float As[128 * 68];
  __shared__ float Ws[32 * 68];
  const int tid = threadIdx.x;
  const int n0 = blockIdx.x * 32;
  const int p  = blockIdx.y;
  const int tx = tid & 7, ty = tid >> 3;
  const int lr = tid >> 4, lc4 = (tid & 15) * 4;
  float acc[4][4] = {};
  const int kend = p * KS + KS;
  for (int k0 = p * KS; k0 < kend; k0 += 64) {
#pragma unroll
    for (int pp = 0; pp < 8; ++pp) {
      int row = input[pp * 16 + lr];
      *(float4*)(As + (pp * 16 + lr) * 68 + lc4) =
          *(const float4*)(emb + (size_t)row * K + k0 + lc4);
    }
#pragma unroll
    for (int pp = 0; pp < 2; ++pp)
      *(float4*)(Ws + (pp * 16 + lr) * 68 + lc4) =
          *(const float4*)(W + (size_t)(n0 + pp * 16 + lr) * K + k0 + lc4);
    __syncthreads();
#pragma unroll
    for (int kk = 0; kk < 16; ++kk) {
      float4 av[4], wv[4];
#pragma unroll
      for (int i = 0; i < 4; i++) av[i] = *(const float4*)(As + (ty * 4 + i) * 68 + kk * 4);
#pragma unroll
      for (int j = 0; j < 4; j++) wv[j] = *(const float4*)(Ws + (tx * 4 + j) * 68 + kk * 4);
#pragma unroll
      for (int i = 0; i < 4; i++)
#pragma unroll
        for (int j = 0; j < 4; j++) {
          acc[i][j] = fmaf(av[i].x, wv[j].x, acc[i][j]);
          acc[i][j] = fmaf(av[i].y, wv[j].y, acc[i][j]);
          acc[i][j] = fmaf(av[i].z, wv[j].z, acc[i][j]);
          acc[i][j] = fmaf(av[i].w, wv[j].w, acc[i][j]);
        }
    }
    __syncthreads();
  }
#pragma unroll
  for (int i = 0; i < 4; i++)
#pragma unroll
    for (int j = 0; j < 4; j++)
      partial[((size_t)p * 128 + ty * 4 + i) * N + n0 + tx * 4 + j] = acc[i][j];
}

__global__ __launch_bounds__(256)
void reduce_partial(const float* __restrict__ partial, const float* __restrict__ bias,
                    float* __restrict__ C, int N, int P)
{
  int idx = blockIdx.x * 256 + threadIdx.x;
  int n = idx % N;
  float s = bias ? bias[n] : 0.f;
  for (int p = 0; p < P; ++p) s += partial[(size_t)p * 128 * N + idx];
  C[idx] = s;
}

__global__ __launch_bounds__(256)
void reduce_partial_bf16(const float* __restrict__ partial, const float* __restrict__ bias,
                         __bf16* __restrict__ C, int N, int P)
{
  int idx = blockIdx.x * 256 + threadIdx.x;
  int n = idx % N;
  float s = bias ? bias[n] : 0.f;
  for (int p = 0; p < P; ++p) s += partial[(size_t)p * 128 * N + idx];
  C[idx] = (__bf16)s;
}

// ------------- 256^2 8-phase MFMA attention feature GEMM (T3+T4+T5) -------------
// Identical K-loop to R8 (thrice-verified); epilogue folds the sWs split-K
// reduction (16 L2-hot partials per column) — deletes a critical-path launch.
__global__ __launch_bounds__(512, 1)
void feat_mfma256_kernel(const __bf16* __restrict__ enc, const __bf16* __restrict__ Wh,
                         const float* __restrict__ pSWS, const float* __restrict__ cov,
                         const float* __restrict__ wcv, const float* __restrict__ ab,
                         const float* __restrict__ av_, float* __restrict__ e_part)
{
  __shared__ __attribute__((aligned(16))) __bf16 As[2][2][128 * 64];  // [dbuf][m-half]
  __shared__ __attribute__((aligned(16))) __bf16 Bs[2][2][128 * 64];  // [dbuf][n-half]
  const int tid  = threadIdx.x;
  const int lane = tid & 63, wid = tid >> 6;   // 8 waves
  const int wr = wid >> 2, wc = wid & 3;       // 2 x 4; wave owns 128x64 output
  const int bid = blockIdx.x;
  const int swz = (bid & 7) * 128 + (bid >> 3);  // bijective XCD swizzle (nwg=1024)
  const int mt = swz >> 2, nt = swz & 3;
  const int bs0 = mt * 256;
  const int n0  = nt * 256;
  const int b   = bs0 >> 9;

  const int scb = ((tid & 7) * 16) ^ (((tid >> 3) & 7) << 4);
  const __bf16* aS[2][2];
  const __bf16* bS[2][2];
#pragma unroll
  for (int h = 0; h < 2; ++h)
#pragma unroll
    for (int q = 0; q < 2; ++q) {
      int r = h * 128 + q * 64 + (tid >> 3);
      aS[h][q] = enc + (size_t)(bs0 + r) * H_ + (scb >> 1);
      bS[h][q] = Wh  + (size_t)(n0  + r) * H_ + (scb >> 1);
    }
  const int ldsQ0 = tid * 16, ldsQ1 = 8192 + tid * 16;

  const int lrow = lane & 15, kbase = (lane >> 4) << 4;
  const int bh = wc >> 1;
  int aO[8][2], bO[4][2];
#pragma unroll
  for (int m = 0; m < 8; ++m) {
    int rh = m * 16 + lrow, sw = (rh & 7) << 4;
    aO[m][0] = rh * 128 + (kbase ^ sw);
    aO[m][1] = rh * 128 + ((64 + kbase) ^ sw);
  }
#pragma unroll
  for (int n = 0; n < 4; ++n) {
    int rh = (wc & 1) * 64 + n * 16 + lrow, sw = (rh & 7) << 4;
    bO[n][0] = rh * 128 + (kbase ^ sw);
    bO[n][1] = rh * 128 + ((64 + kbase) ^ sw);
  }

  f32x4 acc[8][4];
#pragma unroll
  for (int i = 0; i < 8; i++)
#pragma unroll
    for (int j = 0; j < 4; j++) acc[i][j] = (f32x4){0.f, 0.f, 0.f, 0.f};
  bf16x8 bfv[4][2];

#define STG_A(d, h, ofs)                                                       \
  { gload_lds16(aS[h][0] + (ofs), (char*)As[d][h] + ldsQ0);                    \
    gload_lds16(aS[h][1] + (ofs), (char*)As[d][h] + ldsQ1); }
#define STG_B(d, h, ofs)                                                       \
  { gload_lds16(bS[h][0] + (ofs), (char*)Bs[d][h] + ldsQ0);                    \
    gload_lds16(bS[h][1] + (ofs), (char*)Bs[d][h] + ldsQ1); }
#define BAR()                                                                  \
  { __builtin_amdgcn_sched_barrier(0); __builtin_amdgcn_s_barrier();           \
    __builtin_amdgcn_sched_barrier(0); }
#define LGKM0()                                                                \
  { asm volatile("s_waitcnt lgkmcnt(0)" ::: "memory");                         \
    __builtin_amdgcn_sched_barrier(0); }
#define VMC(n)                                                                 \
  { asm volatile("s_waitcnt vmcnt(" #n ")" ::: "memory");                      \
    __builtin_amdgcn_sched_barrier(0); }
#define RD_B(d)                                                                \
  { _Pragma("unroll")                                                          \
    for (int n = 0; n < 4; ++n) {                                              \
      bfv[n][0] = *(const bf16x8*)((const char*)Bs[d][bh] + bO[n][0]);         \
      bfv[n][1] = *(const bf16x8*)((const char*)Bs[d][bh] + bO[n][1]);         \
    } }
#define PH(d, q, STGSTMT, TAILWAIT)                                            \
  {                                                                            \
    bf16x8 x00 = *(const bf16x8*)((const char*)As[d][wr] + aO[2*(q)][0]);      \
    bf16x8 x01 = *(const bf16x8*)((const char*)As[d][wr] + aO[2*(q)][1]);      \
    bf16x8 x10 = *(const bf16x8*)((const char*)As[d][wr] + aO[2*(q)+1][0]);    \
    bf16x8 x11 = *(const bf16x8*)((const char*)As[d][wr] + aO[2*(q)+1][1]);    \
    STGSTMT;                                                                   \
    BAR(); LGKM0();                                                            \
    __builtin_amdgcn_s_setprio(1);                                             \
    _Pragma("unroll")                                                          \
    for (int n = 0; n < 4; ++n) {                                              \
      acc[2*(q)][n]   = __builtin_amdgcn_mfma_f32_16x16x32_bf16(x00, bfv[n][0], acc[2*(q)][n], 0, 0, 0);   \
      acc[2*(q)][n]   = __builtin_amdgcn_mfma_f32_16x16x32_bf16(x01, bfv[n][1], acc[2*(q)][n], 0, 0, 0);   \
      acc[2*(q)+1][n] = __builtin_amdgcn_mfma_f32_16x16x32_bf16(x10, bfv[n][0], acc[2*(q)+1][n], 0, 0, 0); \
      acc[2*(q)+1][n] = __builtin_amdgcn_mfma_f32_16x16x32_bf16(x11, bfv[n][1], acc[2*(q)+1][n], 0, 0, 0); \
    }                                                                          \
    __builtin_amdgcn_s_setprio(0);                                             \
    TAILWAIT; BAR();                                                           \
  }

  STG_B(0, 0, 0) STG_B(0, 1, 0) STG_A(0, 0, 0) STG_A(0, 1, 0)
  STG_B(1, 0, 64) STG_B(1, 1, 64)
  VMC(4); BAR();

#pragma unroll 1
  for (int i = 0; i < 7; ++i) {
    RD_B(0);
    PH(0, 0, STG_A(1, 0, 64), )
    PH(0, 1, STG_A(1, 1, 64), )
    PH(0, 2, STG_B(0, 0, 128), )
    PH(0, 3, STG_B(0, 1, 128), VMC(4))
    RD_B(1);
    PH(1, 0, STG_A(0, 0, 128), )
    PH(1, 1, STG_A(0, 1, 128), )
    PH(1, 2, STG_B(1, 0, 192), )
    PH(1, 3, STG_B(1, 1, 192), VMC(4))
#pragma unroll
    for (int h = 0; h < 2; ++h)
#pragma unroll
      for (int q = 0; q < 2; ++q) { aS[h][q] += 128; bS[h][q] += 128; }
  }
  RD_B(0);
  PH(0, 0, STG_A(1, 0, 64), )
  PH(0, 1, STG_A(1, 1, 64), )
  PH(0, 2, , )
  PH(0, 3, , VMC(0))
  RD_B(1);
  PH(1, 0, , )
  PH(1, 1, , )
  PH(1, 2, , )
  PH(1, 3, , )
  __syncthreads();
#undef STG_A
#undef STG_B
#undef BAR
#undef LGKM0
#undef VMC
#undef RD_B
#undef PH

  // epilogue: sWs (16 split-K partials, L2-hot) + cov*wc + ab, fast-tanh, *av, reduce
  float rowsum[8][4];
#pragma unroll
  for (int m = 0; m < 8; m++)
#pragma unroll
    for (int j = 0; j < 4; j++) rowsum[m][j] = 0.f;

#pragma unroll
  for (int n = 0; n < 4; ++n) {
    int col_g = n0 + wc * 64 + n * 16 + (lane & 15);
    float sw = 0.f;
#pragma unroll
    for (int p = 0; p < 16; ++p) sw += pSWS[((size_t)p * 128 + b) * H_ + col_g];
    float wc_n = wcv[col_g], ab_n = ab[col_g], av_n = av_[col_g];
#pragma unroll
    for (int m = 0; m < 8; ++m) {
#pragma unroll
      for (int j = 0; j < 4; ++j) {
        int row_l = wr * 128 + m * 16 + ((lane >> 4) << 2) + j;
        float val = acc[m][n][j] + sw + cov[bs0 + row_l] * wc_n + ab_n;
        rowsum[m][j] += fast_tanh(val) * av_n;
      }
    }
  }
#pragma unroll
  for (int m = 0; m < 8; ++m)
#pragma unroll
    for (int j = 0; j < 4; ++j) {
      float v = rowsum[m][j];
      v += __shfl_xor(v, 1);
      v += __shfl_xor(v, 2);
      v += __shfl_xor(v, 4);
      v += __shfl_xor(v, 8);
      rowsum[m][j] = v;
    }
  float (*red)[4] = (float(*)[4])As;
  if ((lane & 15) == 0) {
#pragma unroll
    for (int m = 0; m < 8; ++m)
#pragma unroll
      for (int j = 0; j < 4; ++j)
        red[wr * 128 + m * 16 + ((lane >> 4) << 2) + j][wc] = rowsum[m][j];
  }
  __syncthreads();
  if (tid < 256)
    e_part[(size_t)nt * (B_ * S_) + bs0 + tid] =
        red[tid][0] + red[tid][1] + red[tid][2] + red[tid][3];
}

// ------------- MFMA logits GEMM with reg-prefetch of next W k-slice -------------
__global__ __launch_bounds__(256)
void logits_mfma_kernel(const __bf16* __restrict__ A, const float* __restrict__ W,
                        const float* __restrict__ bias, float* __restrict__ out0)
{
  __shared__ __attribute__((aligned(16))) __bf16 As[BM * BK];
  __shared__ __attribute__((aligned(16))) __bf16 Bs[BN * BK];
  const int tid  = threadIdx.x;
  const int lane = tid & 63, wid = tid >> 6;
  const int wr = wid >> 1, wcc = wid & 1;
  const int n0 = blockIdx.x * BN;

  f32x4 acc[4][4];
#pragma unroll
  for (int i = 0; i < 4; i++)
#pragma unroll
    for (int j = 0; j < 4; j++) acc[i][j] = (f32x4){0.f, 0.f, 0.f, 0.f};

  const float* wsrc[8];
  int wdst[8];
#pragma unroll
  for (int p = 0; p < 8; ++p) {
    int idx = p * 1024 + tid * 4;
    int r = idx >> 6, c = idx & 63;
    int row_g = n0 + r; if (row_g >= V_) row_g = V_ - 1;
    wsrc[p] = W + (size_t)row_g * F_ + c;
    wdst[p] = r * 128 + ((c * 2) ^ ((r & 7) << 4));
  }
  float4 wreg[8];
#pragma unroll
  for (int p = 0; p < 8; ++p) wreg[p] = *(const float4*)(wsrc[p]);

  for (int k0 = 0; k0 < F_; k0 += BK) {
#pragma unroll
    for (int p = 0; p < 4; ++p) {
      int off = p * 4096 + tid * 16;
      int r = off >> 7, cb = off & 127;
      int scb = cb ^ ((r & 7) << 4);
      gload_lds16(A + (size_t)r * F_ + k0 + (scb >> 1), (char*)As + off);
    }
#pragma unroll
    for (int p = 0; p < 8; ++p) {
      union { __bf16 h[4]; uint2 u; } t;
      t.h[0] = (__bf16)wreg[p].x; t.h[1] = (__bf16)wreg[p].y;
      t.h[2] = (__bf16)wreg[p].z; t.h[3] = (__bf16)wreg[p].w;
      *(uint2*)((char*)Bs + wdst[p]) = t.u;
    }
    __syncthreads();
    if (k0 + BK < F_) {
#pragma unroll
      for (int p = 0; p < 8; ++p) wreg[p] = *(const float4*)(wsrc[p] + k0 + BK);
    }

    bf16x8 af[4][2], bfv[4][2];
#pragma unroll
    for (int m = 0; m < 4; ++m) {
      int row = wr * 64 + m * 16 + (lane & 15);
      int swz = (row & 7) << 4;
#pragma unroll
      for (int kk = 0; kk < 2; ++kk) {
        int kb = kk * 64 + ((lane >> 4) << 4);
        af[m][kk] = *(const bf16x8*)((const char*)As + row * 128 + (kb ^ swz));
      }
    }
#pragma unroll
    for (int n = 0; n < 4; ++n) {
      int row = wcc * 64 + n * 16 + (lane & 15);
      int swz = (row & 7) << 4;
#pragma unroll
      for (int kk = 0; kk < 2; ++kk) {
        int kb = kk * 64 + ((lane >> 4) << 4);
        bfv[n][kk] = *(const bf16x8*)((const char*)Bs + row * 128 + (kb ^ swz));
      }
    }
#pragma unroll
    for (int m = 0; m < 4; ++m)
#pragma unroll
      for (int n = 0; n < 4; ++n)
#pragma unroll
        for (int kk = 0; kk < 2; ++kk)
          acc[m][n] = __builtin_amdgcn_mfma_f32_16x16x32_bf16(af[m][kk], bfv[n][kk], acc[m][n], 0, 0, 0);
    __syncthreads();
  }

#pragma unroll
  for (int m = 0; m < 4; ++m) {
#pragma unroll
    for (int n = 0; n < 4; ++n) {
      int col_g = n0 + wcc * 64 + n * 16 + (lane & 15);
      if (col_g >= V_) continue;
      float bv = bias[col_g];
#pragma unroll
      for (int j = 0; j < 4; ++j) {
        int row = wr * 64 + m * 16 + ((lane >> 4) << 2) + j;
        out0[(size_t)row * EV_ + col_g] = acc[m][n][j] + bv;
      }
    }
  }
}

// ---------------- softmax over S + renorm + coverage ----------------
__global__ __launch_bounds__(512)
void softmax_a_kernel(const float* __restrict__ e_part, const float* __restrict__ mask,
                      const float* __restrict__ cov, float* __restrict__ a_ws,
                      float* __restrict__ out_a, float* __restrict__ out_cov)
{
  const int b = blockIdx.x;
  const int s = threadIdx.x;
  __shared__ float red[512];
  float e = 0.f;
  for (int kt = 0; kt < 4; ++kt) e += e_part[(size_t)kt * (B_ * S_) + b * S_ + s];
  red[s] = e;
  __syncthreads();
  for (int st = 256; st > 0; st >>= 1) {
    if (s < st) red[s] = fmaxf(red[s], red[s + st]);
    __syncthreads();
  }
  float mx = red[0];
  __syncthreads();
  float ex = expf(e - mx) * mask[b * S_ + s];
  red[s] = ex;
  __syncthreads();
  for (int st = 256; st > 0; st >>= 1) {
    if (s < st) red[s] += red[s + st];
    __syncthreads();
  }
  float a = ex / red[0];
  a_ws[b * S_ + s] = a;
  out_a[b * S_ + s] = a;
  out_cov[b * S_ + s] = cov[b * S_ + s] + a;
}

// ---------------- context[b,h] = sum_s a[b,s] * enc_h[b,s,h]  (bf16 enc) ----------------
__global__ __launch_bounds__(256)
void context_kernel(const float* __restrict__ a_ws, const __bf16* __restrict__ enc,
                    float* __restrict__ ctx)
{
  const int b = blockIdx.y, q = blockIdx.x;
  const int lane = threadIdx.x & 63, w = threadIdx.x >> 6;
  const int h0 = q * 256 + lane * 4;
  __shared__ float al[S_];
  __shared__ float part[4][256];
  for (int i = threadIdx.x; i < S_; i += 256) al[i] = a_ws[b * S_ + i];
  __syncthreads();
  float acc0 = 0.f, acc1 = 0.f, acc2 = 0.f, acc3 = 0.f;
  const __bf16* ep = enc + (size_t)b * S_ * H_ + h0;
#pragma unroll 4
  for (int s = w * 128; s < w * 128 + 128; ++s) {
    bf16x4 v = *(const bf16x4*)(ep + (size_t)s * H_);
    float a = al[s];
    acc0 = fmaf(a, (float)v[0], acc0);
    acc1 = fmaf(a, (float)v[1], acc1);
    acc2 = fmaf(a, (float)v[2], acc2);
    acc3 = fmaf(a, (float)v[3], acc3);
  }
  part[w][lane * 4 + 0] = acc0;
  part[w][lane * 4 + 1] = acc1;
  part[w][lane * 4 + 2] = acc2;
  part[w][lane * 4 + 3] = acc3;
  __syncthreads();
  if (threadIdx.x < 256) {
    int o = threadIdx.x;
    ctx[b * H_ + q * 256 + o] = part[0][o] + part[1][o] + part[2][o] + part[3][o];
  }
}

// ---------------- GRU with folded split-K partial reductions (gi + gh) ----------------
__global__ __launch_bounds__(256)
void gru_kernel(const float* __restrict__ pgi, const float* __restrict__ pgh,
                const float* __restrict__ b_ih, const float* __restrict__ b_hh,
                const float* __restrict__ h_att, float* __restrict__ h_new_ws,
                float* __restrict__ out_h)
{
  int idx = blockIdx.x * 256 + threadIdx.x;
  int b = idx >> 10, h = idx & 1023;
  float ir = b_ih[h], iz = b_ih[H_ + h], in_ = b_ih[2 * H_ + h];
  float hr = b_hh[h], hz = b_hh[H_ + h], hn = b_hh[2 * H_ + h];
#pragma unroll
  for (int p = 0; p < 8; ++p) {
    const float* gp = pgi + (size_t)p * 128 * 3072 + (size_t)b * 3072;
    ir += gp[h]; iz += gp[H_ + h]; in_ += gp[2 * H_ + h];
    const float* hp = pgh + (size_t)p * 128 * 3072 + (size_t)b * 3072;
    hr += hp[h]; hz += hp[H_ + h]; hn += hp[2 * H_ + h];
  }
  float r = 1.f / (1.f + expf(-(ir + hr)));
  float z = 1.f / (1.f + expf(-(iz + hz)));
  float n = tanhf(in_ + r * hn);
  float ha = h_att[(size_t)b * H_ + h];
  float hv = (1.f - z) * n + z * ha;
  h_new_ws[idx] = hv;
  out_h[idx] = hv;
}

// ---------------- merged vocab-stats (blocks 0..B-1, float2) + pgen (blocks B..2B-1) ----------------
__global__ __launch_bounds__(512)
void stats_pgen_kernel(const float* __restrict__ logits, float* __restrict__ vmax,
                       float* __restrict__ vsum, const float* __restrict__ context,
                       const float* __restrict__ h_new, const int* __restrict__ input,
                       const float* __restrict__ emb, const float* __restrict__ wgen_w,
                       const float* __restrict__ wgen_b, float* __restrict__ pgen)
{
  __shared__ float red[512];
  if (blockIdx.x < B_) {
    int b = blockIdx.x;
    const float* row = logits + (size_t)b * EV_;
    float m = -1e30f;
    for (int v = threadIdx.x * 2; v < V_; v += 1024) {
      float2 x = *(const float2*)(row + v);
      m = fmaxf(m, fmaxf(x.x, x.y));
    }
    red[threadIdx.x] = m;
    __syncthreads();
    for (int st = 256; st > 0; st >>= 1) {
      if (threadIdx.x < st) red[threadIdx.x] = fmaxf(red[threadIdx.x], red[threadIdx.x + st]);
      __syncthreads();
    }
    m = red[0];
    __syncthreads();
    float ssum = 0.f;
    for (int v = threadIdx.x * 2; v < V_; v += 1024) {
      float2 x = *(const float2*)(row + v);
      ssum += expf(x.x - m) + expf(x.y - m);
    }
    red[threadIdx.x] = ssum;
    __syncthreads();
    for (int st = 256; st > 0; st >>= 1) {
      if (threadIdx.x < st) red[threadIdx.x] += red[threadIdx.x + st];
      __syncthreads();
    }
    if (threadIdx.x == 0) { vmax[b] = m; vsum[b] = red[0]; }
  } else {
    int b = blockIdx.x - B_;
    const float* erow = emb + (size_t)input[b] * F_;
    float acc = 0.f;
    for (int j = threadIdx.x; j < H_; j += 512) acc = fmaf(context[b * H_ + j], wgen_w[j], acc);
    for (int j = threadIdx.x; j < H_; j += 512) acc = fmaf(h_new[b * H_ + j], wgen_w[H_ + j], acc);
    for (int j = threadIdx.x; j < F_; j += 512) acc = fmaf(erow[j], wgen_w[2 * H_ + j], acc);
    red[threadIdx.x] = acc;
    __syncthreads();
    for (int st = 256; st > 0; st >>= 1) {
      if (threadIdx.x < st) red[threadIdx.x] += red[threadIdx.x + st];
      __syncthreads();
    }
    if (threadIdx.x == 0) {
      float p = 1.f / (1.f + expf(-(red[0] + wgen_b[0])));
      p = fminf(fmaxf(p, 0.001f), 0.999f);
      pgen[b] = p;
    }
  }
}

__global__ void final_kernel(float* __restrict__ out0, const float* __restrict__ vmax,
                             const float* __restrict__ vsum, const float* __restrict__ pgen)
{
  int b = blockIdx.y;
  int v = blockIdx.x * 256 + threadIdx.x;
  if (v >= EV_) return;
  float* row = out0 + (size_t)b * EV_;
  if (v < V_) row[v] = pgen[b] * expf(row[v] - vmax[b]) / vsum[b];
  else row[v] = 0.f;
}

__global__ void scatter_kernel(const int* __restrict__ ref2tgt, const float* __restrict__ a_ws,
                               const float* __restrict__ pgen, float* __restrict__ out0)
{
  int b = blockIdx.x;
  int s = threadIdx.x;
  float w = (1.f - pgen[b]) * a_ws[b * S_ + s];
  int t = ref2tgt[b * S_ + s];
  atomicAdd(&out0[(size_t)b * EV_ + t], w);
}

extern "C" void kernel_launch(void* const* d_in, const int* in_sizes, int n_in,
                              void* d_out, int out_size, void* d_ws, size_t ws_size,
                              hipStream_t stream)
{
  const int*   input   = (const int*)d_in[0];
  const float* hidden  = (const float*)d_in[1];
  const float* enc     = (const float*)d_in[2];
  const float* mask    = (const float*)d_in[3];
  const float* cov     = (const float*)d_in[5];
  const int*   ref2tgt = (const int*)d_in[6];
  const float* emb     = (const float*)d_in[7];
  const float* W_ih    = (const float*)d_in[8];
  const float* W_hh    = (const float*)d_in[9];
  const float* b_ih    = (const float*)d_in[10];
  const float* b_hh    = (const float*)d_in[11];
  const float* e2v1_w  = (const float*)d_in[12];
  const float* e2v1_b  = (const float*)d_in[13];
  const float* e2v2_w  = (const float*)d_in[14];
  const float* e2v2_b  = (const float*)d_in[15];
  const float* fc_w    = (const float*)d_in[16];
  const float* fc_b    = (const float*)d_in[17];
  const float* wgen_w  = (const float*)d_in[18];
  const float* wgen_b  = (const float*)d_in[19];
  const float* att_Wh  = (const float*)d_in[20];
  const float* att_Ws  = (const float*)d_in[21];
  const float* att_wc  = (const float*)d_in[22];
  const float* att_b   = (const float*)d_in[23];
  const float* att_v   = (const float*)d_in[24];

  char* w = (char*)d_ws;
  __bf16* enc_h  = (__bf16*)w;  w += (size_t)B_ * S_ * H_ * 2;   // 134.2 MB
  __bf16* Wh_h   = (__bf16*)w;  w += (size_t)H_ * H_ * 2;        // 2 MB
  __bf16* out1_h = (__bf16*)w;  w += (size_t)B_ * F_ * 2;
  float* e_part  = (float*)w;   w += (size_t)4 * B_ * S_ * 4;
  float* a_ws    = (float*)w;   w += (size_t)B_ * S_ * 4;
  float* context = (float*)w;   w += (size_t)B_ * H_ * 4;
  float* h_att   = (float*)w;   w += (size_t)B_ * H_ * 4;
  float* h_new   = (float*)w;   w += (size_t)B_ * H_ * 4;
  float* pgen    = (float*)w;   w += 128 * 4;
  float* vmax    = (float*)w;   w += 128 * 4;
  float* vsum    = (float*)w;   w += 128 * 4;
  float* pA      = (float*)w;   w += (size_t)16 * 128 * 1024 * 4;  // 8 MB (sWs / fc / out1 partials)
  float* pB      = (float*)w;   w += (size_t)8 * 128 * 3072 * 4;   // 12.6 MB (gi partials)
  float* pC      = (float*)w;   w += (size_t)8 * 128 * 3072 * 4;   // 12.6 MB (gh partials)

  float* out0    = (float*)d_out;
  float* out_h   = out0 + (size_t)B_ * EV_;
  float* out_cov = out_h + (size_t)B_ * H_;
  float* out_a   = out_cov + (size_t)B_ * S_;

  // 1. combined bf16 casts (enc + Wh) — dedicated kernel, full occupancy
  cast_both_kernel<<<4096, 256, 0, stream>>>(enc, enc_h, att_Wh, Wh_h);
  // 2. sWs split-K partials (reduction folded into feat epilogue)
  gemm_splitk<<<dim3(32, 16), 256, 0, stream>>>(hidden, att_Ws, pA, H_, H_, 64);
  // 3. fused attention feature GEMM (256^2, 8-phase)
  feat_mfma256_kernel<<<dim3(1024), 512, 0, stream>>>(enc_h, Wh_h, pA, cov, att_wc, att_b, att_v, e_part);
  // 4. softmax + coverage
  softmax_a_kernel<<<B_, 512, 0, stream>>>(e_part, mask, cov, a_ws, out_a, out_cov);
  // 5. context from bf16 enc
  context_kernel<<<dim3(4, B_), 256, 0, stream>>>(a_ws, enc_h, context);
  // 6. h_att = [hidden, context] @ fc_w^T + fc_b
  gemm_splitk_cat<<<dim3(32, 16), 256, 0, stream>>>(hidden, context, fc_w, pA, H_, 2 * H_, 128);
  reduce_partial<<<512, 256, 0, stream>>>(pA, fc_b, h_att, H_, 16);
  // 7. GRU gate partials (reductions folded into gru)
  gemm_splitk_gather<<<dim3(96, 8), 256, 0, stream>>>(input, emb, W_ih, pB, 3 * H_, F_, 64);
  gemm_splitk<<<dim3(96, 8), 256, 0, stream>>>(h_att, W_hh, pC, 3 * H_, H_, 128);
  gru_kernel<<<(B_ * H_) / 256, 256, 0, stream>>>(pB, pC, b_ih, b_hh, h_att, h_new, out_h);
  // 8. out1 = h_new @ e2v1^T + b  (reduce straight to bf16)
  gemm_splitk<<<dim3(16, 16), 256, 0, stream>>>(h_new, e2v1_w, pA, F_, H_, 64);
  reduce_partial_bf16<<<256, 256, 0, stream>>>(pA, e2v1_b, out1_h, F_, 16);
  // 9. vocab logits + merged stats/pgen + pointer mix
  logits_mfma_kernel<<<dim3((V_ + BN - 1) / BN), 256, 0, stream>>>(out1_h, e2v2_w, e2v2_b, out0);
  stats_pgen_kernel<<<2 * B_, 512, 0, stream>>>(out0, vmax, vsum, context, h_new, input, emb,
                                                wgen_w, wgen_b, pgen);
  final_kernel<<<dim3((EV_ + 255) / 256, B_), 256, 0, stream>>>(out0, vmax, vsum, pgen);
  scatter_kernel<<<B_, 512, 0, stream>>>(ref2tgt, a_ws, pgen, out0);
}